// Round 9
// baseline (1657.792 us; speedup 1.0000x reference)
//
#include <hip/hip_runtime.h>

// y = alpha*(x @ Q^T) + bias; alpha = mean|W|; Q = clip(round(W/alpha),-1,1)
// x:(2,4096,4096) f32, W:(16384,4096) f32, bias:(16384) f32, out f32.
#define M_DIM 8192
#define N_DIM 16384
#define K_DIM 4096
#define NT 64  // K_DIM / 64

typedef unsigned short u16;
typedef unsigned int u32;
typedef __attribute__((ext_vector_type(8))) short bf16x8;
typedef __attribute__((ext_vector_type(8))) unsigned short u16x8;
typedef __attribute__((ext_vector_type(16))) float f32x16;

#define MFMA32(a, b, c) __builtin_amdgcn_mfma_f32_32x32x16_bf16(a, b, c, 0, 0, 0)
#define SGB(mask, n) __builtin_amdgcn_sched_group_barrier((mask), (n), 0)

__device__ __forceinline__ void gload16(const u16* g, u16* l) {
  __builtin_amdgcn_global_load_lds((const __attribute__((address_space(1))) void*)g,
                                   (__attribute__((address_space(3))) void*)l, 16, 0, 0);
}

// ---------------- alpha = mean(|W|), f64 two-pass reduction ----------------
__global__ void reduce_abs1(const float* __restrict__ w, double* __restrict__ partials) {
  const float4* w4 = (const float4*)w;
  size_t base = (size_t)blockIdx.x * 4096 + threadIdx.x;
  double s = 0.0;
#pragma unroll
  for (int i = 0; i < 16; ++i) {
    float4 v = w4[base + (size_t)i * 256];
    s += (double)fabsf(v.x); s += (double)fabsf(v.y);
    s += (double)fabsf(v.z); s += (double)fabsf(v.w);
  }
#pragma unroll
  for (int off = 32; off > 0; off >>= 1) s += __shfl_down(s, off, 64);
  __shared__ double red[4];
  int wv = threadIdx.x >> 6, lane = threadIdx.x & 63;
  if (lane == 0) red[wv] = s;
  __syncthreads();
  if (threadIdx.x == 0) partials[blockIdx.x] = (red[0] + red[1]) + (red[2] + red[3]);
}

__global__ void reduce_abs2(const double* __restrict__ partials,
                            double* __restrict__ alpha_d, float* __restrict__ alpha_f) {
  double s = 0.0;
  for (int i = threadIdx.x; i < 4096; i += 256) s += partials[i];
#pragma unroll
  for (int off = 32; off > 0; off >>= 1) s += __shfl_down(s, off, 64);
  __shared__ double red[4];
  int wv = threadIdx.x >> 6, lane = threadIdx.x & 63;
  if (lane == 0) red[wv] = s;
  __syncthreads();
  if (threadIdx.x == 0) {
    double total = (red[0] + red[1]) + (red[2] + red[3]);
    double a = total / (double)((long long)N_DIM * (long long)K_DIM);
    alpha_d[0] = a;
    alpha_f[0] = (float)a;
  }
}

// ---------------- W -> ternary Q stored as bf16 (+1/0/-1 exact) ----------------
__global__ void quant_w(const float* __restrict__ w, const double* __restrict__ alpha_d,
                        u16* __restrict__ q) {
  double inv = 1.0 / alpha_d[0];
  size_t i8 = (size_t)blockIdx.x * 256 + threadIdx.x;
  const float4* w4 = (const float4*)w;
  float4 v0 = w4[i8 * 2], v1 = w4[i8 * 2 + 1];
  float vv[8] = {v0.x, v0.y, v0.z, v0.w, v1.x, v1.y, v1.z, v1.w};
  u16x8 o;
#pragma unroll
  for (int j = 0; j < 8; ++j) {
    double r = rint((double)vv[j] * inv);
    u16 enc = 0;
    if (r >= 1.0) enc = 0x3F80u;
    else if (r <= -1.0) enc = 0xBF80u;
    o[j] = enc;
  }
  *((u16x8*)q + i8) = o;
}

// ---------------- x fp32 -> bf16 (RNE) ----------------
__global__ void conv_x(const float* __restrict__ x, u16* __restrict__ xb) {
  size_t i8 = (size_t)blockIdx.x * 256 + threadIdx.x;
  const float4* x4 = (const float4*)x;
  float4 v0 = x4[i8 * 2], v1 = x4[i8 * 2 + 1];
  float vv[8] = {v0.x, v0.y, v0.z, v0.w, v1.x, v1.y, v1.z, v1.w};
  u16x8 o;
#pragma unroll
  for (int j = 0; j < 8; ++j) {
    u32 u = __float_as_uint(vv[j]);
    u += 0x7FFFu + ((u >> 16) & 1u);
    o[j] = (u16)(u >> 16);
  }
  *((u16x8*)xb + i8) = o;
}

// ------- 256x256-tile bf16 GEMM: 32x32x16 MFMA + frag-packed LDS -------
// 512 threads = 8 waves (2M x 4N); per-wave 128x64 = acc[4][2] f32x16
// (128 AGPR; + ~110 VGPR stays under the 256/wave unified budget, R7 lesson).
// LDS frag-packed: chunk (half, sub, ks, lane) at linear offset -> every
// ds_read_b128 is wave-uniform base + lane*16 = contiguous 1KB: ZERO bank
// conflicts by construction. The layout permutation lives entirely in the
// per-thread global source offsets of global_load_lds (m173 pattern).
// 32x32x16: MFMA wall 2483->2066 cy/CU/K-tile, half the instructions.
// Schedule (R8 skeleton): depth-1 opposite-parity prefetch, single tile-end
// vmcnt(0)+barrier, SGB-pinned batches {6 ds_reads(ks+1) | 8 MFMA(ks)}.
__global__ __launch_bounds__(512, 2) void gemm256(
    const u16* __restrict__ A, const u16* __restrict__ Bq,
    const float* __restrict__ bias, const float* __restrict__ alpha_f,
    float* __restrict__ C) {
  // [parity][half(2)][sub(4)][ks(4)][lane(64)][8 u16] = 32 KiB per parity
  __shared__ __align__(16) u16 Alds[2][16384];
  __shared__ __align__(16) u16 Blds[2][16384];

  const int t = threadIdx.x;
  const int wv = t >> 6, l = t & 63;
  const int wr = wv >> 2, wc = wv & 3;  // 2M x 4N wave grid
  const int l31 = l & 31, hi = l >> 5;
  const int l8 = l * 8;  // u16 units: lane's 16B slot within a frag chunk

  // XCD-bijective swizzle (2048 % 8 == 0) + 8(tm) x 64(tn) supertiles
  const int bid = blockIdx.x;
  const int wg = (bid & 7) * 256 + (bid >> 3);
  const int grp = wg >> 9, rem = wg & 511;
  const int tm = grp * 8 + (rem & 7);  // 0..31
  const int tn = rem >> 3;             // 0..63

  const u16* Ag = A + (size_t)tm * 256 * K_DIM;
  const u16* Bg = Bq + (size_t)tn * 256 * K_DIM;

  // Staging: chunk q in [0,1024) per 128-row half decomposes as
  // lane=q&63, ks=(q>>6)&3, sub=q>>8; it holds global
  // [row = sub*32 + (lane&31)][k = ks*16 + (lane>>5)*8 .. +8).
  // Thread t stages chunks q0=t, q1=512+t of each half (A:2 halves, B:2).
  int so[2], doff[2][2];  // so: per-lane global elem offset; doff[h][slot]: u16 LDS
#pragma unroll
  for (int s = 0; s < 2; ++s) {
    int q = s * 512 + t;
    int ln = q & 63, ks = (q >> 6) & 3, sub = q >> 8;
    int row = sub * 32 + (ln & 31);
    int k = ks * 16 + (ln >> 5) * 8;
    so[s] = row * K_DIM + k;
#pragma unroll
    for (int h = 0; h < 2; ++h)
      doff[h][s] = (h * 1024 + s * 512 + wv * 64) * 8;  // wave-uniform dest base
  }

  // Frag read bases (u16 units), wave-uniform + l8:
  // A frag (msub, ks): Alds[par] + wr*8192 + (msub*4+ks)*512 + l8
  // B frag (nn,  ks): Blds[par] + (wc>>1)*8192 + (wc&1)*4096 + (nn*4+ks)*512 + l8
  const int ABase = wr * 8192;
  const int BBase = (wc >> 1) * 8192 + (wc & 1) * 4096;
#define LDA(par, msub, ks) (*(const bf16x8*)(&Alds[par][ABase + ((msub) * 4 + (ks)) * 512 + l8]))
#define LDB(par, nn, ks)   (*(const bf16x8*)(&Blds[par][BBase + ((nn) * 4 + (ks)) * 512 + l8]))

  f32x16 acc[4][2];
#pragma unroll
  for (int m = 0; m < 4; ++m)
#pragma unroll
    for (int n = 0; n < 2; ++n)
      acc[m][n] = (f32x16){0.f};

  // stage K-tile g into parity g&1: 8 gload16 per thread (A,B x 2 halves x 2 slots)
  auto stage = [&](int g) {
    if (g < NT) {
      const int par = g & 1;
      const int kb = g * 64;
#pragma unroll
      for (int h = 0; h < 2; ++h) {
#pragma unroll
        for (int s = 0; s < 2; ++s) {
          gload16(Ag + (size_t)h * (128 * K_DIM) + kb + so[s], &Alds[par][doff[h][s]]);
          gload16(Bg + (size_t)h * (128 * K_DIM) + kb + so[s], &Blds[par][doff[h][s]]);
        }
      }
    }
  };

#define MFMA8(aset, bset)                                                      \
  _Pragma("unroll") for (int m = 0; m < 4; ++m)                                \
    _Pragma("unroll") for (int n = 0; n < 2; ++n)                              \
      acc[m][n] = MFMA32(aset[m], bset[n], acc[m][n])

  // one K-tile: pre-read ks0; 4 batches {reads(ks+1) | stage | 8 MFMA(ks)}
#define K_TILE(kt, par)                                                        \
  {                                                                            \
    bf16x8 a0[4], a1[4], b0[2], b1[2];                                         \
    /* pre: ks0 -> a0,b0 */                                                    \
    _Pragma("unroll") for (int m = 0; m < 4; ++m) a0[m] = LDA(par, m, 0);      \
    b0[0] = LDB(par, 0, 0); b0[1] = LDB(par, 1, 0);                            \
    SGB(0x100, 6);                                                             \
    /* b0: reads ks1 -> a1,b1; stage tile kt+1 (8 gloads); MFMA ks0 */         \
    _Pragma("unroll") for (int m = 0; m < 4; ++m) a1[m] = LDA(par, m, 1);      \
    b1[0] = LDB(par, 0, 1); b1[1] = LDB(par, 1, 1);                            \
    stage((kt) + 1);                                                           \
    MFMA8(a0, b0);                                                             \
    SGB(0x100, 6); SGB(0x20, 8); SGB(0x8, 8);                                  \
    /* b1: reads ks2 -> a0,b0; MFMA ks1 */                                     \
    _Pragma("unroll") for (int m = 0; m < 4; ++m) a0[m] = LDA(par, m, 2);      \
    b0[0] = LDB(par, 0, 2); b0[1] = LDB(par, 1, 2);                            \
    MFMA8(a1, b1);                                                             \
    SGB(0x100, 6); SGB(0x8, 8);                                                \
    /* b2: reads ks3 -> a1,b1; MFMA ks2 */                                     \
    _Pragma("unroll") for (int m = 0; m < 4; ++m) a1[m] = LDA(par, m, 3);      \
    b1[0] = LDB(par, 0, 3); b1[1] = LDB(par, 1, 3);                            \
    MFMA8(a0, b0);                                                             \
    SGB(0x100, 6); SGB(0x8, 8);                                                \
    /* b3: MFMA ks3 */                                                         \
    MFMA8(a1, b1);                                                             \
    SGB(0x8, 8);                                                               \
    /* tile end: kt+1 stages (issued in b0) landed; rendezvous */              \
    asm volatile("s_waitcnt vmcnt(0)" ::: "memory");                           \
    __builtin_amdgcn_s_barrier();                                              \
  }

  // prologue: stage tile 0 (parity 0); wait; barrier
  stage(0);
  asm volatile("s_waitcnt vmcnt(0)" ::: "memory");
  __builtin_amdgcn_s_barrier();

  for (int kt2 = 0; kt2 < NT; kt2 += 2) {
    K_TILE(kt2, 0);
    K_TILE(kt2 + 1, 1);
  }
#undef K_TILE
#undef MFMA8
#undef LDA
#undef LDB

  // epilogue: y = alpha*acc + bias.
  // 32x32 C/D (m74/m101-verified): col=l&31, row=(r&3)+8*(r>>2)+4*(l>>5).
  const float alpha = alpha_f[0];
#pragma unroll
  for (int nn = 0; nn < 2; ++nn) {
    const int col = tn * 256 + wc * 64 + nn * 32 + l31;
    const float bs = bias[col];
#pragma unroll
    for (int m = 0; m < 4; ++m) {
      const int rowbase = tm * 256 + wr * 128 + m * 32 + hi * 4;
      float* Cp = C + (size_t)rowbase * N_DIM + col;
#pragma unroll
      for (int r = 0; r < 16; ++r) {
        const int dr = (r & 3) + 8 * (r >> 2);
        Cp[(size_t)dr * N_DIM] = alpha * acc[m][nn][r] + bs;
      }
    }
  }
}

extern "C" void kernel_launch(void* const* d_in, const int* in_sizes, int n_in,
                              void* d_out, int out_size, void* d_ws, size_t ws_size,
                              hipStream_t stream) {
  const float* x = (const float*)d_in[0];
  const float* w = (const float*)d_in[1];
  const float* bias = (const float*)d_in[2];
  float* out = (float*)d_out;

  char* ws = (char*)d_ws;
  double* alpha_d = (double*)ws;
  float* alpha_f = (float*)(ws + 8);
  double* partials = (double*)(ws + 16);
  u16* xb = (u16*)(ws + 65536);                 // 64 MiB (M*K bf16)
  u16* qb = (u16*)(ws + 65536 + 67108864ULL);   // 128 MiB (N*K bf16)

  reduce_abs1<<<4096, 256, 0, stream>>>(w, partials);
  reduce_abs2<<<1, 256, 0, stream>>>(partials, alpha_d, alpha_f);
  quant_w<<<32768, 256, 0, stream>>>(w, alpha_d, qb);
  conv_x<<<16384, 256, 0, stream>>>(x, xb);
  gemm256<<<2048, 512, 0, stream>>>(xb, qb, bias, alpha_f, out);
}

// Round 10
// 1254.840 us; speedup vs baseline: 1.3211x; 1.3211x over previous
//
#include <hip/hip_runtime.h>

// y = alpha*(x @ Q^T) + bias; alpha = mean|W|; Q = clip(round(W/alpha),-1,1)
// x:(2,4096,4096) f32, W:(16384,4096) f32, bias:(16384) f32, out f32.
#define M_DIM 8192
#define N_DIM 16384
#define K_DIM 4096
#define NT 64  // K_DIM / 64

typedef unsigned short u16;
typedef unsigned int u32;
typedef __attribute__((ext_vector_type(8))) short bf16x8;
typedef __attribute__((ext_vector_type(8))) unsigned short u16x8;
typedef __attribute__((ext_vector_type(4))) float f32x4;

#define MFMA(a, b, c) __builtin_amdgcn_mfma_f32_16x16x32_bf16(a, b, c, 0, 0, 0)
#define SGB(mask, n) __builtin_amdgcn_sched_group_barrier((mask), (n), 0)

__device__ __forceinline__ void gload16(const u16* g, u16* l) {
  __builtin_amdgcn_global_load_lds((const __attribute__((address_space(1))) void*)g,
                                   (__attribute__((address_space(3))) void*)l, 16, 0, 0);
}

// ---------------- alpha = mean(|W|), f64 two-pass reduction ----------------
__global__ void reduce_abs1(const float* __restrict__ w, double* __restrict__ partials) {
  const float4* w4 = (const float4*)w;
  size_t base = (size_t)blockIdx.x * 4096 + threadIdx.x;
  double s = 0.0;
#pragma unroll
  for (int i = 0; i < 16; ++i) {
    float4 v = w4[base + (size_t)i * 256];
    s += (double)fabsf(v.x); s += (double)fabsf(v.y);
    s += (double)fabsf(v.z); s += (double)fabsf(v.w);
  }
#pragma unroll
  for (int off = 32; off > 0; off >>= 1) s += __shfl_down(s, off, 64);
  __shared__ double red[4];
  int wv = threadIdx.x >> 6, lane = threadIdx.x & 63;
  if (lane == 0) red[wv] = s;
  __syncthreads();
  if (threadIdx.x == 0) partials[blockIdx.x] = (red[0] + red[1]) + (red[2] + red[3]);
}

__global__ void reduce_abs2(const double* __restrict__ partials,
                            double* __restrict__ alpha_d, float* __restrict__ alpha_f) {
  double s = 0.0;
  for (int i = threadIdx.x; i < 4096; i += 256) s += partials[i];
#pragma unroll
  for (int off = 32; off > 0; off >>= 1) s += __shfl_down(s, off, 64);
  __shared__ double red[4];
  int wv = threadIdx.x >> 6, lane = threadIdx.x & 63;
  if (lane == 0) red[wv] = s;
  __syncthreads();
  if (threadIdx.x == 0) {
    double total = (red[0] + red[1]) + (red[2] + red[3]);
    double a = total / (double)((long long)N_DIM * (long long)K_DIM);
    alpha_d[0] = a;
    alpha_f[0] = (float)a;
  }
}

// ---------------- W -> ternary Q stored as bf16 (+1/0/-1 exact) ----------------
__global__ void quant_w(const float* __restrict__ w, const double* __restrict__ alpha_d,
                        u16* __restrict__ q) {
  double inv = 1.0 / alpha_d[0];
  size_t i8 = (size_t)blockIdx.x * 256 + threadIdx.x;
  const float4* w4 = (const float4*)w;
  float4 v0 = w4[i8 * 2], v1 = w4[i8 * 2 + 1];
  float vv[8] = {v0.x, v0.y, v0.z, v0.w, v1.x, v1.y, v1.z, v1.w};
  u16x8 o;
#pragma unroll
  for (int j = 0; j < 8; ++j) {
    double r = rint((double)vv[j] * inv);
    u16 enc = 0;
    if (r >= 1.0) enc = 0x3F80u;
    else if (r <= -1.0) enc = 0xBF80u;
    o[j] = enc;
  }
  *((u16x8*)q + i8) = o;
}

// ---------------- x fp32 -> bf16 (RNE) ----------------
__global__ void conv_x(const float* __restrict__ x, u16* __restrict__ xb) {
  size_t i8 = (size_t)blockIdx.x * 256 + threadIdx.x;
  const float4* x4 = (const float4*)x;
  float4 v0 = x4[i8 * 2], v1 = x4[i8 * 2 + 1];
  float vv[8] = {v0.x, v0.y, v0.z, v0.w, v1.x, v1.y, v1.z, v1.w};
  u16x8 o;
#pragma unroll
  for (int j = 0; j < 8; ++j) {
    u32 u = __float_as_uint(vv[j]);
    u += 0x7FFFu + ((u >> 16) & 1u);
    o[j] = (u16)(u >> 16);
  }
  *((u16x8*)xb + i8) = o;
}

// ------- 256x256-tile bf16 GEMM, SGB batch pipeline + T5 setprio -------
// R8 structure verbatim (best measured: 1010us, MfmaUtil 49.4%), single added
// variable: s_setprio(1)/(0) around each 8-MFMA batch (T5). R8's batch
// structure has no intra-tile barriers -> waves drift across batch positions
// -> role diversity on each SIMD -> setprio lets the MFMA-holding wave
// preempt read/stage-issuing waves (m218b/m224: +21-39% on phase-split
// schedules; null only on lockstep structures, m190).
__global__ __launch_bounds__(512, 2) void gemm256(
    const u16* __restrict__ A, const u16* __restrict__ Bq,
    const float* __restrict__ bias, const float* __restrict__ alpha_f,
    float* __restrict__ C) {
  __shared__ __align__(16) u16 Alds[2][2][128 * 64];  // [parity][half][r*64+k]
  __shared__ __align__(16) u16 Blds[2][2][128 * 64];

  const int t = threadIdx.x;
  const int wv = t >> 6, l = t & 63;
  const int wr = wv >> 2, wc = wv & 3;  // 2M x 4N wave grid
  const int lr = l & 15, lk = l >> 4;

  // XCD-bijective swizzle (2048 % 8 == 0) + 8(tm) x 64(tn) supertiles
  const int bid = blockIdx.x;
  const int wg = (bid & 7) * 256 + (bid >> 3);
  const int grp = wg >> 9, rem = wg & 511;
  const int tm = grp * 8 + (rem & 7);  // 0..31
  const int tn = rem >> 3;             // 0..63

  const u16* Ag = A + (size_t)tm * 256 * K_DIM;
  const u16* Bg = Bq + (size_t)tn * 256 * K_DIM;

  // staging source offsets (pre-swizzled global source, linear LDS dest)
  const int q0 = t, q1 = 512 + t;
  const int r0 = q0 >> 3, c0 = (q0 & 7) ^ (r0 & 7);
  const int r1 = q1 >> 3, c1 = (q1 & 7) ^ (r1 & 7);
  const size_t so0 = (size_t)r0 * K_DIM + c0 * 8;
  const size_t so1 = (size_t)r1 * K_DIM + c1 * 8;
  const int do0 = (wv * 64) * 8;          // u16 units (wave-uniform dest base)
  const int do1 = (512 + wv * 64) * 8;

  // Swizzled frag read bases (u16 units). For frag row r = sub*16 + lr:
  // r&7 == lr&7, so offset = sub*1024 + fb[ks];  sub*1024 folds to imm offset.
  const int fb0 = lr * 64 + ((lk ^ (lr & 7)) * 8);
  const int fb1 = lr * 64 + (((4 + lk) ^ (lr & 7)) * 8);
#define LDF(ptr, sub, ks) (*(const bf16x8*)((ptr) + (sub) * 1024 + ((ks) ? fb1 : fb0)))

  f32x4 acc[8][4];
#pragma unroll
  for (int mi = 0; mi < 8; ++mi)
#pragma unroll
    for (int ni = 0; ni < 4; ++ni)
      acc[mi][ni] = (f32x4){0.f, 0.f, 0.f, 0.f};

  // stage one half-tile H (2 x global_load_lds per wave); no-op past last tile
  auto stage = [&](int H) {
    int g = H >> 2;
    if (g < NT) {
      int sub = H & 3;  // 0:B0 1:B1 2:A0 3:A1
      const u16* src;
      u16* dst;
      if (sub < 2) { src = Bg + (size_t)sub * (128 * K_DIM); dst = &Blds[g & 1][sub][0]; }
      else         { src = Ag + (size_t)(sub - 2) * (128 * K_DIM); dst = &Alds[g & 1][sub - 2][0]; }
      src += g * 64;
      gload16(src + so0, dst + do0);
      gload16(src + so1, dst + do1);
    }
  };

#define MFMA8(accrow, aset, bset, nbase)                                       \
  do {                                                                         \
    __builtin_amdgcn_s_setprio(1);                                             \
    _Pragma("unroll") for (int m = 0; m < 4; ++m)                              \
      _Pragma("unroll") for (int n = 0; n < 2; ++n)                            \
        acc[(accrow) + m][(nbase) + n] =                                       \
            MFMA(aset[m], bset[n], acc[(accrow) + m][(nbase) + n]);            \
    __builtin_amdgcn_s_setprio(0);                                             \
  } while (0)

  // one K-tile = pre-reads + 8 SGB-pinned {reads(j+1) | 8 MFMA(j)} batches
#define K_TILE(kt, par)                                                        \
  {                                                                            \
    const u16* Ar = &Alds[par][wr][0];                                         \
    const u16* Br = &Blds[par][wc >> 1][0] + (wc & 1) * 4096;                  \
    bf16x8 A0[4], A1[4], A2[4], A3[4], Ba0[2], Bb0[2], Ba1[2], Bb1[2];         \
    /* pre: A0(4) + Ba0(2) */                                                  \
    _Pragma("unroll") for (int m = 0; m < 4; ++m) A0[m] = LDF(Ar, m, 0);       \
    Ba0[0] = LDF(Br, 0, 0); Ba0[1] = LDF(Br, 1, 0);                            \
    SGB(0x100, 6);                                                             \
    /* b0: R{Bb0, A1[0-1]}; stage h0,h1(kt+1); M: acc[0-3][0-1]+=A0*Ba0 */     \
    Bb0[0] = LDF(Br, 2, 0); Bb0[1] = LDF(Br, 3, 0);                            \
    A1[0] = LDF(Ar, 0, 1); A1[1] = LDF(Ar, 1, 1);                              \
    stage(4 * (kt) + 4); stage(4 * (kt) + 5);                                  \
    MFMA8(0, A0, Ba0, 0);                                                      \
    SGB(0x100, 4); SGB(0x20, 4); SGB(0x8, 8);                                  \
    /* b1: R{A1[2-3], Ba1}; stage h2,h3(kt+1); M: acc[0-3][2-3]+=A0*Bb0 */     \
    A1[2] = LDF(Ar, 2, 1); A1[3] = LDF(Ar, 3, 1);                              \
    Ba1[0] = LDF(Br, 0, 1); Ba1[1] = LDF(Br, 1, 1);                            \
    stage(4 * (kt) + 6); stage(4 * (kt) + 7);                                  \
    MFMA8(0, A0, Bb0, 2);                                                      \
    SGB(0x100, 4); SGB(0x20, 4); SGB(0x8, 8);                                  \
    /* b2: R{Bb1, A2[0-1]}; M: acc[0-3][0-1]+=A1*Ba1 */                        \
    Bb1[0] = LDF(Br, 2, 1); Bb1[1] = LDF(Br, 3, 1);                            \
    A2[0] = LDF(Ar, 4, 0); A2[1] = LDF(Ar, 5, 0);                              \
    MFMA8(0, A1, Ba1, 0);                                                      \
    SGB(0x100, 4); SGB(0x8, 8);                                                \
    /* b3: R{A2[2-3]}; M: acc[0-3][2-3]+=A1*Bb1 */                             \
    A2[2] = LDF(Ar, 6, 0); A2[3] = LDF(Ar, 7, 0);                              \
    MFMA8(0, A1, Bb1, 2);                                                      \
    SGB(0x100, 2); SGB(0x8, 8);                                                \
    /* b4: R{A3[0-1]}; M: acc[4-7][0-1]+=A2*Ba0 */                             \
    A3[0] = LDF(Ar, 4, 1); A3[1] = LDF(Ar, 5, 1);                              \
    MFMA8(4, A2, Ba0, 0);                                                      \
    SGB(0x100, 2); SGB(0x8, 8);                                                \
    /* b5: R{A3[2-3]}; M: acc[4-7][2-3]+=A2*Bb0 */                             \
    A3[2] = LDF(Ar, 6, 1); A3[3] = LDF(Ar, 7, 1);                              \
    MFMA8(4, A2, Bb0, 2);                                                      \
    SGB(0x100, 2); SGB(0x8, 8);                                                \
    /* b6: M: acc[4-7][0-1]+=A3*Ba1 */                                         \
    MFMA8(4, A3, Ba1, 0);                                                      \
    SGB(0x8, 8);                                                               \
    /* b7: M: acc[4-7][2-3]+=A3*Bb1 */                                         \
    MFMA8(4, A3, Bb1, 2);                                                      \
    SGB(0x8, 8);                                                               \
    /* tile end: kt+1 stages (issued b0/b1) landed; rendezvous */              \
    asm volatile("s_waitcnt vmcnt(0)" ::: "memory");                           \
    __builtin_amdgcn_s_barrier();                                              \
  }

  // prologue: stage tile 0 (parity 0); wait; barrier
#pragma unroll
  for (int H = 0; H < 4; ++H) stage(H);
  asm volatile("s_waitcnt vmcnt(0)" ::: "memory");
  __builtin_amdgcn_s_barrier();

  for (int kt2 = 0; kt2 < NT; kt2 += 2) {
    K_TILE(kt2, 0);
    K_TILE(kt2 + 1, 1);
  }
#undef K_TILE
#undef MFMA8
#undef LDF

  // epilogue: y = alpha*acc + bias.  C/D: col=l&15, row=4*(l>>4)+j (m89-verified)
  const float alpha = alpha_f[0];
#pragma unroll
  for (int ni = 0; ni < 4; ++ni) {
    const int col = tn * 256 + wc * 64 + ni * 16 + lr;
    const float bs = bias[col];
#pragma unroll
    for (int mi = 0; mi < 8; ++mi) {
      const int row = tm * 256 + wr * 128 + mi * 16 + lk * 4;
      float* Cp = C + (size_t)row * N_DIM + col;
#pragma unroll
      for (int j = 0; j < 4; ++j)
        Cp[(size_t)j * N_DIM] = alpha * acc[mi][ni][j] + bs;
    }
  }
}

extern "C" void kernel_launch(void* const* d_in, const int* in_sizes, int n_in,
                              void* d_out, int out_size, void* d_ws, size_t ws_size,
                              hipStream_t stream) {
  const float* x = (const float*)d_in[0];
  const float* w = (const float*)d_in[1];
  const float* bias = (const float*)d_in[2];
  float* out = (float*)d_out;

  char* ws = (char*)d_ws;
  double* alpha_d = (double*)ws;
  float* alpha_f = (float*)(ws + 8);
  double* partials = (double*)(ws + 16);
  u16* xb = (u16*)(ws + 65536);                 // 64 MiB (M*K bf16)
  u16* qb = (u16*)(ws + 65536 + 67108864ULL);   // 128 MiB (N*K bf16)

  reduce_abs1<<<4096, 256, 0, stream>>>(w, partials);
  reduce_abs2<<<1, 256, 0, stream>>>(partials, alpha_d, alpha_f);
  quant_w<<<32768, 256, 0, stream>>>(w, alpha_d, qb);
  conv_x<<<16384, 256, 0, stream>>>(x, xb);
  gemm256<<<2048, 512, 0, stream>>>(xb, qb, bias, alpha_f, out);
}

// Round 11
// 1167.327 us; speedup vs baseline: 1.4202x; 1.0750x over previous
//
#include <hip/hip_runtime.h>

// y = alpha*(x @ Q^T) + bias; alpha = mean|W|; Q = clip(round(W/alpha),-1,1)
// x:(2,4096,4096) f32, W:(16384,4096) f32, bias:(16384) f32, out f32.
#define M_DIM 8192
#define N_DIM 16384
#define K_DIM 4096
#define NT 128  // K_DIM / 32

typedef unsigned short u16;
typedef unsigned int u32;
typedef __attribute__((ext_vector_type(8))) short bf16x8;
typedef __attribute__((ext_vector_type(8))) unsigned short u16x8;
typedef __attribute__((ext_vector_type(4))) float f32x4;

#define MFMA(a, b, c) __builtin_amdgcn_mfma_f32_16x16x32_bf16(a, b, c, 0, 0, 0)
#define SGB(mask, n) __builtin_amdgcn_sched_group_barrier((mask), (n), 0)

__device__ __forceinline__ void gload16(const u16* g, u16* l) {
  __builtin_amdgcn_global_load_lds((const __attribute__((address_space(1))) void*)g,
                                   (__attribute__((address_space(3))) void*)l, 16, 0, 0);
}

// ---------------- alpha = mean(|W|), f64 two-pass reduction ----------------
__global__ void reduce_abs1(const float* __restrict__ w, double* __restrict__ partials) {
  const float4* w4 = (const float4*)w;
  size_t base = (size_t)blockIdx.x * 4096 + threadIdx.x;
  double s = 0.0;
#pragma unroll
  for (int i = 0; i < 16; ++i) {
    float4 v = w4[base + (size_t)i * 256];
    s += (double)fabsf(v.x); s += (double)fabsf(v.y);
    s += (double)fabsf(v.z); s += (double)fabsf(v.w);
  }
#pragma unroll
  for (int off = 32; off > 0; off >>= 1) s += __shfl_down(s, off, 64);
  __shared__ double red[4];
  int wv = threadIdx.x >> 6, lane = threadIdx.x & 63;
  if (lane == 0) red[wv] = s;
  __syncthreads();
  if (threadIdx.x == 0) partials[blockIdx.x] = (red[0] + red[1]) + (red[2] + red[3]);
}

__global__ void reduce_abs2(const double* __restrict__ partials,
                            double* __restrict__ alpha_d, float* __restrict__ alpha_f) {
  double s = 0.0;
  for (int i = threadIdx.x; i < 4096; i += 256) s += partials[i];
#pragma unroll
  for (int off = 32; off > 0; off >>= 1) s += __shfl_down(s, off, 64);
  __shared__ double red[4];
  int wv = threadIdx.x >> 6, lane = threadIdx.x & 63;
  if (lane == 0) red[wv] = s;
  __syncthreads();
  if (threadIdx.x == 0) {
    double total = (red[0] + red[1]) + (red[2] + red[3]);
    double a = total / (double)((long long)N_DIM * (long long)K_DIM);
    alpha_d[0] = a;
    alpha_f[0] = (float)a;
  }
}

// ---------------- W -> ternary Q stored as bf16 (+1/0/-1 exact) ----------------
__global__ void quant_w(const float* __restrict__ w, const double* __restrict__ alpha_d,
                        u16* __restrict__ q) {
  double inv = 1.0 / alpha_d[0];
  size_t i8 = (size_t)blockIdx.x * 256 + threadIdx.x;
  const float4* w4 = (const float4*)w;
  float4 v0 = w4[i8 * 2], v1 = w4[i8 * 2 + 1];
  float vv[8] = {v0.x, v0.y, v0.z, v0.w, v1.x, v1.y, v1.z, v1.w};
  u16x8 o;
#pragma unroll
  for (int j = 0; j < 8; ++j) {
    double r = rint((double)vv[j] * inv);
    u16 enc = 0;
    if (r >= 1.0) enc = 0x3F80u;
    else if (r <= -1.0) enc = 0xBF80u;
    o[j] = enc;
  }
  *((u16x8*)q + i8) = o;
}

// ---------------- x fp32 -> bf16 (RNE) ----------------
__global__ void conv_x(const float* __restrict__ x, u16* __restrict__ xb) {
  size_t i8 = (size_t)blockIdx.x * 256 + threadIdx.x;
  const float4* x4 = (const float4*)x;
  float4 v0 = x4[i8 * 2], v1 = x4[i8 * 2 + 1];
  float vv[8] = {v0.x, v0.y, v0.z, v0.w, v1.x, v1.y, v1.z, v1.w};
  u16x8 o;
#pragma unroll
  for (int j = 0; j < 8; ++j) {
    u32 u = __float_as_uint(vv[j]);
    u += 0x7FFFu + ((u >> 16) & 1u);
    o[j] = (u16)(u >> 16);
  }
  *((u16x8*)xb + i8) = o;
}

// ------- 256x256-tile bf16 GEMM: BK=32, 4-buffer ring, TRUE counted vmcnt -------
// 512 threads = 8 waves (2M x 4N); per-wave 128x64 = acc[8][4] f32x4 (128 AGPR).
// LDS: 4 ring buffers x {A 256x32, B 256x32} bf16 = 128 KiB.
// T4 (m218, +38%@4k): tile g stages tile g+3 into buffer (g+3)&3; tile-end wait
// is vmcnt(8) = "tile g+1's 4 loads done" (issued 3 tiles ~3600cy ago), leaving
// the 8 newer loads IN FLIGHT across the barrier -> the VMEM queue never
// drains; no wave rendezvous on a fresh load tail (the R6-R10 drain-0 stall).
// Tail peels: kt==NT-3 -> vmcnt(4), kt==NT-2 -> vmcnt(0), last tile: nothing.
// Per tile: 12 ds_reads + 4 gloads front-loaded into first 3 SGB batches,
// 32 MFMAs in 8 batches of 4. No intra-tile barriers (R6: stage writes never
// alias current reads; overwrite of buffer (g-1)&3 is tile-end-barrier-ordered).
// No setprio (R10: -7% on this structure). Both-sides XOR swizzle (4-chunk rows).
__global__ __launch_bounds__(512, 2) void gemm256(
    const u16* __restrict__ A, const u16* __restrict__ Bq,
    const float* __restrict__ bias, const float* __restrict__ alpha_f,
    float* __restrict__ C) {
  __shared__ __align__(16) u16 Alds[4][256 * 32];  // 16 KiB per buffer
  __shared__ __align__(16) u16 Blds[4][256 * 32];

  const int t = threadIdx.x;
  const int wv = t >> 6, l = t & 63;
  const int wr = wv >> 2, wc = wv & 3;  // 2M x 4N wave grid
  const int lr = l & 15, lk = l >> 4;

  // XCD-bijective swizzle (2048 % 8 == 0) + 8(tm) x 64(tn) supertiles
  const int bid = blockIdx.x;
  const int wg = (bid & 7) * 256 + (bid >> 3);
  const int grp = wg >> 9, rem = wg & 511;
  const int tm = grp * 8 + (rem & 7);  // 0..31
  const int tn = rem >> 3;             // 0..63

  const u16* Ag = A + (size_t)tm * 256 * K_DIM;
  const u16* Bg = Bq + (size_t)tn * 256 * K_DIM;

  // Staging: 16B chunk q in [0,1024) of a [256][32] tile: row=q>>2, physical
  // chunk pc=q&3 holds logical chunk c = pc ^ (row&3) (involution; read side
  // applies the same XOR). Thread t owns q = t and q = 512+t; LDS dest is
  // wave-uniform base + lane*16 (linear), source is pre-swizzled.
  int so[2], dof[2];
#pragma unroll
  for (int s = 0; s < 2; ++s) {
    int q = s * 512 + t;
    int row = q >> 2, c = (q & 3) ^ (row & 3);
    so[s] = row * K_DIM + c * 8;
    dof[s] = (s * 512 + wv * 64) * 8;  // u16 units
  }

  // Frag read base (u16): row = sub*16 + lr (row&3 == lr&3), chunk lk^(lr&3);
  // per-sub offset sub*512 folds to an immediate.
  const int fb = lr * 32 + ((lk ^ (lr & 3)) * 8);
#define LDA(b, m) (*(const bf16x8*)(&Alds[b][wr * 4096 + (m) * 512 + fb]))
#define LDB(b, n) (*(const bf16x8*)(&Blds[b][wc * 2048 + (n) * 512 + fb]))

  f32x4 acc[8][4];
#pragma unroll
  for (int mi = 0; mi < 8; ++mi)
#pragma unroll
    for (int ni = 0; ni < 4; ++ni)
      acc[mi][ni] = (f32x4){0.f, 0.f, 0.f, 0.f};

  // stage K-tile g into ring buffer g&3 (A: 2 gloads; B: 2 gloads per thread)
  auto stageA = [&](int g) {
    if (g < NT) {
      const u16* src = Ag + g * 32;
      gload16(src + so[0], &Alds[g & 3][dof[0]]);
      gload16(src + so[1], &Alds[g & 3][dof[1]]);
    }
  };
  auto stageB = [&](int g) {
    if (g < NT) {
      const u16* src = Bg + g * 32;
      gload16(src + so[0], &Blds[g & 3][dof[0]]);
      gload16(src + so[1], &Blds[g & 3][dof[1]]);
    }
  };

#define MFMA4(m0, m1, n0, n1, aset, bset)                                      \
  acc[m0][n0] = MFMA(aset[0], bset[0], acc[m0][n0]);                           \
  acc[m0][n1] = MFMA(aset[0], bset[1], acc[m0][n1]);                           \
  acc[m1][n0] = MFMA(aset[1], bset[0], acc[m1][n0]);                           \
  acc[m1][n1] = MFMA(aset[1], bset[1], acc[m1][n1])

  // one K-tile; b = kt&3 compile-time at each expansion
#define K_TILE(kt, b)                                                          \
  {                                                                            \
    bf16x8 a01[2], a23[2], a45[2], a67[2], b01[2], b23[2];                     \
    /* pre: A0,A1,B0,B1 */                                                     \
    a01[0] = LDA(b, 0); a01[1] = LDA(b, 1);                                    \
    b01[0] = LDB(b, 0); b01[1] = LDB(b, 1);                                    \
    SGB(0x100, 4);                                                             \
    /* b0: R{A2,A3,B2}; stage A(kt+3); M{A01 x B01} */                         \
    a23[0] = LDA(b, 2); a23[1] = LDA(b, 3);                                    \
    b23[0] = LDB(b, 2);                                                        \
    stageA((kt) + 3);                                                          \
    MFMA4(0, 1, 0, 1, a01, b01);                                               \
    SGB(0x100, 3); SGB(0x20, 2); SGB(0x8, 4);                                  \
    /* b1: R{A4,A5,B3}; stage B(kt+3); M{A23 x B01} */                         \
    a45[0] = LDA(b, 4); a45[1] = LDA(b, 5);                                    \
    b23[1] = LDB(b, 3);                                                        \
    stageB((kt) + 3);                                                          \
    MFMA4(2, 3, 0, 1, a23, b01);                                               \
    SGB(0x100, 3); SGB(0x20, 2); SGB(0x8, 4);                                  \
    /* b2: R{A6,A7}; M{A01 x B23} */                                           \
    a67[0] = LDA(b, 6); a67[1] = LDA(b, 7);                                    \
    MFMA4(0, 1, 2, 3, a01, b23);                                               \
    SGB(0x100, 2); SGB(0x8, 4);                                                \
    /* b3-b7: remaining MFMA quads */                                          \
    MFMA4(2, 3, 2, 3, a23, b23);                                               \
    SGB(0x8, 4);                                                               \
    MFMA4(4, 5, 0, 1, a45, b01);                                               \
    SGB(0x8, 4);                                                               \
    MFMA4(4, 5, 2, 3, a45, b23);                                               \
    SGB(0x8, 4);                                                               \
    MFMA4(6, 7, 0, 1, a67, b01);                                               \
    SGB(0x8, 4);                                                               \
    MFMA4(6, 7, 2, 3, a67, b23);                                               \
    SGB(0x8, 4);                                                               \
    /* tile end: counted wait -- only tile kt+1's loads must be done */        \
    if ((kt) < NT - 3) {                                                       \
      asm volatile("s_waitcnt vmcnt(8)" ::: "memory");                         \
      __builtin_amdgcn_s_barrier();                                            \
    } else if ((kt) == NT - 3) {                                               \
      asm volatile("s_waitcnt vmcnt(4)" ::: "memory");                         \
      __builtin_amdgcn_s_barrier();                                            \
    } else if ((kt) == NT - 2) {                                               \
      asm volatile("s_waitcnt vmcnt(0)" ::: "memory");                         \
      __builtin_amdgcn_s_barrier();                                            \
    } /* last tile: no wait, epilogue follows */                               \
  }

  // prologue: stage tiles 0,1,2 (12 loads); wait for tile 0's 4 (vmcnt(8))
  stageA(0); stageB(0);
  stageA(1); stageB(1);
  stageA(2); stageB(2);
  asm volatile("s_waitcnt vmcnt(8)" ::: "memory");
  __builtin_amdgcn_s_barrier();

  for (int kt4 = 0; kt4 < NT; kt4 += 4) {
    K_TILE(kt4 + 0, 0);
    K_TILE(kt4 + 1, 1);
    K_TILE(kt4 + 2, 2);
    K_TILE(kt4 + 3, 3);
  }
#undef K_TILE
#undef MFMA4
#undef LDA
#undef LDB

  // epilogue: y = alpha*acc + bias.  C/D: col=l&15, row=4*(l>>4)+j (m89-verified)
  const float alpha = alpha_f[0];
#pragma unroll
  for (int ni = 0; ni < 4; ++ni) {
    const int col = tn * 256 + wc * 64 + ni * 16 + lr;
    const float bs = bias[col];
#pragma unroll
    for (int mi = 0; mi < 8; ++mi) {
      const int row = tm * 256 + wr * 128 + mi * 16 + lk * 4;
      float* Cp = C + (size_t)row * N_DIM + col;
#pragma unroll
      for (int j = 0; j < 4; ++j)
        Cp[(size_t)j * N_DIM] = alpha * acc[mi][ni][j] + bs;
    }
  }
}

extern "C" void kernel_launch(void* const* d_in, const int* in_sizes, int n_in,
                              void* d_out, int out_size, void* d_ws, size_t ws_size,
                              hipStream_t stream) {
  const float* x = (const float*)d_in[0];
  const float* w = (const float*)d_in[1];
  const float* bias = (const float*)d_in[2];
  float* out = (float*)d_out;

  char* ws = (char*)d_ws;
  double* alpha_d = (double*)ws;
  float* alpha_f = (float*)(ws + 8);
  double* partials = (double*)(ws + 16);
  u16* xb = (u16*)(ws + 65536);                 // 64 MiB (M*K bf16)
  u16* qb = (u16*)(ws + 65536 + 67108864ULL);   // 128 MiB (N*K bf16)

  reduce_abs1<<<4096, 256, 0, stream>>>(w, partials);
  reduce_abs2<<<1, 256, 0, stream>>>(partials, alpha_d, alpha_f);
  quant_w<<<32768, 256, 0, stream>>>(w, alpha_d, qb);
  conv_x<<<16384, 256, 0, stream>>>(x, xb);
  gemm256<<<2048, 512, 0, stream>>>(xb, qb, bias, alpha_f, out);
}